// Round 7
// baseline (73.267 us; speedup 1.0000x reference)
//
#include <hip/hip_runtime.h>
#include <hip/hip_bf16.h>

#define BATCH 32
#define WW 900
#define CCH 256
#define PVAL 450
#define KHALF 128     // K columns per block (K-split x2)
#define MSTRIP 128    // M rows per block
#define NCHUNK 32     // B rows staged per chunk
#define NCHUNKS 29    // 29*32 = 928 >= 900

typedef __bf16 bf16x8 __attribute__((ext_vector_type(8)));
typedef __bf16 bf16x4 __attribute__((ext_vector_type(4)));
typedef float f32x4 __attribute__((ext_vector_type(4)));

// ws layout (floats): inv [0, 16384) = [64][256]; sums [16384, 16384+segs*64*256)
#define INV_OFF 0
#define SUMS_OFF 16384

// ---------------- norm pass 1: partial sums of squares ----------------
// grid = 2*32*segs blocks; block = 256 threads (thread = channel c)
__global__ void nc_norm_partial(const float* __restrict__ x1,
                                const float* __restrict__ x2,
                                float* __restrict__ sums,
                                int segs, int rowsper) {
    int blk = blockIdx.x;
    int seg = blk % segs;
    int b = (blk / segs) & 31;
    int which = blk / (segs * 32);
    const float* x = which ? x2 : x1;
    int c = threadIdx.x;
    int r0 = seg * rowsper;
    int r1 = r0 + rowsper;
    if (r1 > WW) r1 = WW;
    const float* p = x + ((size_t)b * WW + r0) * CCH + c;
    float s = 0.f;
    #pragma unroll 4
    for (int w = 0; w < r1 - r0; ++w) {
        float v = p[(size_t)w * CCH];
        s = fmaf(v, v, s);
    }
    sums[(((size_t)(which * 32 + b)) * segs + seg) * CCH + c] = s;
}

// ---------------- norm pass 2: inv = rsqrt(max(sum, eps)) ----------------
__global__ void nc_norm_finalize(float* __restrict__ ws, int segs) {
    int i = blockIdx.x * 256 + threadIdx.x;   // wb*256 + c over 64*256
    int c = i & 255;
    int wb = i >> 8;
    const float* s = ws + SUMS_OFF + (size_t)wb * segs * CCH + c;
    float t = 0.f;
    for (int q = 0; q < segs; ++q) t += s[(size_t)q * CCH];
    ws[INV_OFF + i] = rsqrtf(fmaxf(t, 1e-12f));
}

// ---------------- main: GEMM + atomic-free-scatter diagonal reduction ----------------
// grid = 512: b = blockIdx&31, strip = (blockIdx>>5)&7, kh = blockIdx>>8.
// A frags in REGISTERS (loaded once via LDS stage); B chunks double-buffered in LDS.
__global__ __launch_bounds__(256, 2)
void nc_corr(const float* __restrict__ x1,
             const float* __restrict__ x2,
             const float* __restrict__ ws,
             float* __restrict__ out) {
    __shared__ __bf16 Abuf[MSTRIP * KHALF];       // 32 KB (dead after frag load)
    __shared__ __bf16 Bbuf[2][NCHUNK * KHALF];    // 2 x 8 KB
    __shared__ float scratch[4][16][65];          // 16.25 KB
    __shared__ float partial[WW];                 // 3.6 KB

    const int tid = threadIdx.x;
    const int b = blockIdx.x & 31;
    const int strip = (blockIdx.x >> 5) & 7;
    const int kh = blockIdx.x >> 8;
    const int m0 = strip * MSTRIP;
    const int k0 = kh * KHALF;

    const float* __restrict__ inv1 = ws + INV_OFF + b * CCH + k0;
    const float* __restrict__ inv2 = ws + INV_OFF + (BATCH + b) * CCH + k0;
    const float* __restrict__ x1b = x1 + (size_t)b * WW * CCH + k0;
    const float* __restrict__ x2b = x2 + (size_t)b * WW * CCH + k0;

    for (int i = tid; i < WW; i += 256) partial[i] = 0.f;
    for (int i = tid; i < 4 * 16 * 65; i += 256) ((float*)scratch)[i] = 0.f;

    const int lane = tid & 63;
    const int wave = tid >> 6;     // m-slice: rows m0 + wave*32 .. +31
    const int fr = lane & 15;
    const int fq = lane >> 4;

    // coalesced staging coords
    const int sr = tid >> 5;       // 0..7
    const int sg = tid & 31;       // 0..31

    // ---- Stage A once: 128 rows x 128 cols, coalesced, normalized, swizzled ----
    {
        float4 iv1 = *(const float4*)(inv1 + sg * 4);
        #pragma unroll
        for (int k = 0; k < 16; ++k) {
            const int row = sr + 8 * k;        // 0..127
            const int m = m0 + row;
            float4 f = make_float4(0.f, 0.f, 0.f, 0.f);
            if (m < WW) f = *(const float4*)(x1b + (size_t)m * CCH + sg * 4);
            bf16x4 v = { (__bf16)(f.x * iv1.x), (__bf16)(f.y * iv1.y),
                         (__bf16)(f.z * iv1.z), (__bf16)(f.w * iv1.w) };
            *(bf16x4*)(&Abuf[row * KHALF + (((sg >> 1) ^ (row & 7)) << 3) + (sg & 1) * 4]) = v;
        }
    }

    // ---- B staging: coalesced, 4 float4 per thread per chunk ----
    const float4 ivB = *(const float4*)(inv2 + sg * 4);
    float4 st[4];

    auto loadB = [&](int chunk) {
        #pragma unroll
        for (int k = 0; k < 4; ++k) {
            const int row = chunk * NCHUNK + sr + 8 * k;
            st[k] = (row < WW) ? *(const float4*)(x2b + (size_t)row * CCH + sg * 4)
                               : make_float4(0.f, 0.f, 0.f, 0.f);
        }
    };
    auto writeB = [&](int buf) {
        #pragma unroll
        for (int k = 0; k < 4; ++k) {
            const int row = sr + 8 * k;        // 0..31
            float4 f = st[k];
            bf16x4 v = { (__bf16)(f.x * ivB.x), (__bf16)(f.y * ivB.y),
                         (__bf16)(f.z * ivB.z), (__bf16)(f.w * ivB.w) };
            *(bf16x4*)(&Bbuf[buf][row * KHALF + (((sg >> 1) ^ (row & 7)) << 3) + (sg & 1) * 4]) = v;
        }
    };

    loadB(0);
    writeB(0);
    __syncthreads();   // A staged, B chunk0 staged, partial+scratch zeroed

    // ---- A fragments: LDS -> registers, ONCE; pinned so they can't be re-sunk ----
    bf16x8 af[2][4];
    #pragma unroll
    for (int mt = 0; mt < 2; ++mt)
        #pragma unroll
        for (int kk = 0; kk < 4; ++kk) {
            const int row = wave * 32 + mt * 16 + fr;
            const int g = (kk * 4 + fq) ^ (row & 7);
            af[mt][kk] = *(const bf16x8*)(&Abuf[row * KHALF + g * 8]);
        }
    #pragma unroll
    for (int mt = 0; mt < 2; ++mt)
        #pragma unroll
        for (int kk = 0; kk < 4; ++kk)
            asm volatile("" : "+v"(af[mt][kk]));

    int cur = 0;
    for (int chunk = 0; chunk < NCHUNKS; ++chunk) {
        if (chunk + 1 < NCHUNKS) loadB(chunk + 1);   // issue early (T14)

        f32x4 acc[2][2];
        #pragma unroll
        for (int mt = 0; mt < 2; ++mt)
            #pragma unroll
            for (int nt = 0; nt < 2; ++nt)
                acc[mt][nt] = (f32x4){0.f, 0.f, 0.f, 0.f};

        #pragma unroll
        for (int kk = 0; kk < 4; ++kk) {
            bf16x8 bfr[2];
            #pragma unroll
            for (int nt = 0; nt < 2; ++nt) {
                const int row = nt * 16 + fr;
                const int g = (kk * 4 + fq) ^ (row & 7);
                bfr[nt] = *(const bf16x8*)(&Bbuf[cur][row * KHALF + g * 8]);
            }
            #pragma unroll
            for (int mt = 0; mt < 2; ++mt)
                #pragma unroll
                for (int nt = 0; nt < 2; ++nt)
                    acc[mt][nt] = __builtin_amdgcn_mfma_f32_16x16x32_bf16(
                        af[mt][kk], bfr[nt], acc[mt][nt], 0, 0, 0);
        }

        // ---- epilogue: combine equal tile-diagonals, bijective scatter ----
        {
            f32x4 c0 = acc[0][1];                    // dd = 0  (mt - nt = -1)
            f32x4 c1 = acc[0][0] + acc[1][1];        // dd = 1
            f32x4 c2 = acc[1][0];                    // dd = 2
            const int mub = 4 * fq;
            #pragma unroll
            for (int r = 0; r < 4; ++r) {
                const int mu = mub + r;
                const int dr = mu - fr + 15;         // 0..30
                scratch[wave][mu][dr]      = c0[r];
                scratch[wave][mu][dr + 16] = c1[r];
                scratch[wave][mu][dr + 32] = c2[r];
            }
        }

        // ---- per-wave row-sum + direct LDS atomic into partial (no fold stage) ----
        {
            float s = 0.f;
            #pragma unroll
            for (int m = 0; m < 16; ++m) s += scratch[wave][m][lane];
            if (lane < 63) {
                int v = m0 + 32 * wave - 32 * chunk + lane + 1319;  // in [423, 2373]
                if (v >= 1800) v -= 900;
                if (v >= 900) v -= 900;
                unsafeAtomicAdd(&partial[v], s);
            }
        }

        if (chunk + 1 < NCHUNKS) writeB(cur ^ 1);
        __syncthreads();
        cur ^= 1;
    }

    __syncthreads();
    for (int i = tid; i < WW; i += 256)
        unsafeAtomicAdd(&out[(size_t)b * WW + i], partial[i]);  // 16 blocks per batch
}

extern "C" void kernel_launch(void* const* d_in, const int* in_sizes, int n_in,
                              void* d_out, int out_size, void* d_ws, size_t ws_size,
                              hipStream_t stream) {
    const float* x1 = (const float*)d_in[0];
    const float* x2 = (const float*)d_in[1];
    float* out = (float*)d_out;
    float* ws = (float*)d_ws;

    // choose norm split by available workspace (deterministic: ws_size fixed)
    const size_t need15 = (size_t)(SUMS_OFF + 15 * 64 * 256) * sizeof(float);  // ~1.05 MB
    const int segs = (ws_size >= need15) ? 15 : 4;
    const int rowsper = (WW + segs - 1) / segs;   // 60 or 225

    hipMemsetAsync(d_out, 0, (size_t)out_size * sizeof(float), stream);
    nc_norm_partial<<<2 * 32 * segs, 256, 0, stream>>>(x1, x2, ws + SUMS_OFF, segs, rowsper);
    nc_norm_finalize<<<64, 256, 0, stream>>>(ws, segs);
    nc_corr<<<512, 256, 0, stream>>>(x1, x2, ws, out);
}